// Round 6
// baseline (332.008 us; speedup 1.0000x reference)
//
#include <hip/hip_runtime.h>
#include <hip/hip_bf16.h>
#include <stdint.h>

#define D_EMB 128
#define D_NLP 768
#define NKC 12            // 768 / 64 k-chunks

typedef __attribute__((ext_vector_type(8))) short bf16x8;
typedef __attribute__((ext_vector_type(16))) float f32x16;
typedef __attribute__((ext_vector_type(8))) unsigned short u16x8;

__device__ __forceinline__ unsigned short f2bf(float f) {
  unsigned u = __builtin_bit_cast(unsigned, f);
  u += 0x7fffu + ((u >> 16) & 1u);   // RTNE (NaN-free inputs)
  return (unsigned short)(u >> 16);
}

// ---- kernel W: w0 (128x768 f32) -> bf16 row-major; also init mn.
__global__ void kw(const float* __restrict__ w0, unsigned short* __restrict__ w0b,
                   int* __restrict__ mn) {
  int t = blockIdx.x * 256 + threadIdx.x;       // 12288 threads
  if (t == 0) mn[0] = 0x7fffffff;
  if (t >= (D_EMB * D_NLP) / 8) return;
  const float4* src = (const float4*)(w0 + (size_t)t * 8);
  float4 v0 = src[0], v1 = src[1];
  u16x8 o;
  o[0] = f2bf(v0.x); o[1] = f2bf(v0.y); o[2] = f2bf(v0.z); o[3] = f2bf(v0.w);
  o[4] = f2bf(v1.x); o[5] = f2bf(v1.y); o[6] = f2bf(v1.z); o[7] = f2bf(v1.w);
  *(u16x8*)(w0b + (size_t)t * 8) = o;
}

// ---- kernel M: mn = min_e max(ei[0][e], ei[1][e])
__global__ void km(const int* __restrict__ ei, int E, int* __restrict__ mn) {
  int t = blockIdx.x * blockDim.x + threadIdx.x;
  int stride = gridDim.x * blockDim.x;
  int m = 0x7fffffff;
  for (int e = t; e < E; e += stride) {
    int a = ei[e], b = ei[E + e];
    int q = a > b ? a : b;
    m = q < m ? q : m;
  }
  #pragma unroll
  for (int off = 32; off; off >>= 1) {
    int o = __shfl_xor(m, off);
    m = o < m ? o : m;
  }
  if ((threadIdx.x & 63) == 0) atomicMin(mn, m);
}

// ---- kernel C: LDS-free, barrier-free main loop. 8 waves/block; wave (rt,ct)
// owns a 32x32 tile of the 64x128 block output via mfma_f32_32x32x16_bf16.
// A: z0 global->reg (f32) one chunk ahead, cvt_pk->bf16. B: w0b (192KB,
// L2-resident) global->reg ring, one chunk ahead. Cross-wave col reduction
// via 1KB LDS at the end only.
__global__ __launch_bounds__(512) void kc(
    const float* __restrict__ z0, const float* __restrict__ z,
    const unsigned short* __restrict__ w0b, const float* __restrict__ w1,
    const float* __restrict__ prelu_a, float* __restrict__ sv,
    float* __restrict__ ta, float* __restrict__ tb, int N) {
  __shared__ float red[2][32][4];

  const int tid = threadIdx.x;
  const int lane = tid & 63;
  const int wave = tid >> 6;        // 0..7
  const int rt = wave >> 2;         // row-tile 0..1
  const int ct = wave & 3;          // col-tile 0..3
  const int hl = lane >> 5;         // k-half
  const int l31 = lane & 31;
  const int blk = blockIdx.x;

  const int arow = blk * 64 + rt * 32 + l31;
  const int arow_g = min(arow, N - 1);
  const float* aBase = z0 + (size_t)arow_g * D_NLP + hl * 8;
  const unsigned short* bBase = w0b + (size_t)(ct * 32 + l31) * D_NLP + hl * 8;

  f32x16 acc;
  #pragma unroll
  for (int i = 0; i < 16; ++i) acc[i] = 0.f;

  float4 As[8];       // A staging for next chunk (f32)
  bf16x8 Ab[4];       // A fragments, current chunk
  bf16x8 Bf[2][4];    // B ring

  auto loadA = [&](int t) {
    #pragma unroll
    for (int ks = 0; ks < 4; ++ks) {
      const float4* p = (const float4*)(aBase + t * 64 + ks * 16);
      As[2 * ks] = p[0];
      As[2 * ks + 1] = p[1];
    }
  };
  auto loadB = [&](int t, int s) {
    #pragma unroll
    for (int ks = 0; ks < 4; ++ks)
      Bf[s][ks] = *(const bf16x8*)(bBase + t * 64 + ks * 16);
  };
  auto cvtA = [&]() {
    #pragma unroll
    for (int ks = 0; ks < 4; ++ks) {
      unsigned r0, r1, r2, r3;
      asm("v_cvt_pk_bf16_f32 %0, %1, %2" : "=v"(r0) : "v"(As[2*ks].x),   "v"(As[2*ks].y));
      asm("v_cvt_pk_bf16_f32 %0, %1, %2" : "=v"(r1) : "v"(As[2*ks].z),   "v"(As[2*ks].w));
      asm("v_cvt_pk_bf16_f32 %0, %1, %2" : "=v"(r2) : "v"(As[2*ks+1].x), "v"(As[2*ks+1].y));
      asm("v_cvt_pk_bf16_f32 %0, %1, %2" : "=v"(r3) : "v"(As[2*ks+1].z), "v"(As[2*ks+1].w));
      uint4 u = make_uint4(r0, r1, r2, r3);
      Ab[ks] = __builtin_bit_cast(bf16x8, u);
    }
  };

  loadA(0);
  loadB(0, 0);
  #pragma unroll
  for (int t = 0; t < NKC; ++t) {
    cvtA();                                       // consumes As (chunk t)
    if (t + 1 < NKC) { loadA(t + 1); loadB(t + 1, (t + 1) & 1); }
    #pragma unroll
    for (int ks = 0; ks < 4; ++ks)
      acc = __builtin_amdgcn_mfma_f32_32x32x16_bf16(Ab[ks], Bf[t & 1][ks], acc, 0, 0, 0);
  }

  // per-wave partial: prelu * w1c[col], reduce across this tile's 32 cols
  float ap = prelu_a[0];
  float wc = w1[2 * D_EMB + ct * 32 + l31];
  float ps[16];
  #pragma unroll
  for (int r = 0; r < 16; ++r) {
    float h = acc[r];
    float x = h >= 0.f ? h : ap * h;
    ps[r] = x * wc;
  }
  #pragma unroll
  for (int off = 1; off < 32; off <<= 1) {
    #pragma unroll
    for (int r = 0; r < 16; ++r) ps[r] += __shfl_xor(ps[r], off);
  }
  if (l31 == 0) {
    #pragma unroll
    for (int r = 0; r < 16; ++r) {
      int rl = (r & 3) + 8 * (r >> 2) + 4 * hl;   // C/D row map (m74/m101)
      red[rt][rl][ct] = ps[r];
    }
  }
  __syncthreads();

  if (wave < 4) {
    // fused kt: ta/tb for rows blk*64 + wave*16 + [0,16)
    int col16 = lane & 15, kg4 = lane >> 4;
    int myrow = blk * 64 + wave * 16 + col16;
    int rg = min(myrow, N - 1);
    const float* zp = z + (size_t)rg * D_EMB + kg4 * 32;
    const float4* wa4 = (const float4*)(w1 + kg4 * 32);
    const float4* wb4 = (const float4*)(w1 + D_EMB + kg4 * 32);
    float pa = 0.f, pb = 0.f;
    #pragma unroll
    for (int i = 0; i < 8; ++i) {
      float4 zv = ((const float4*)zp)[i];
      float4 wa = wa4[i];
      float4 wb = wb4[i];
      pa += zv.x * wa.x + zv.y * wa.y + zv.z * wa.z + zv.w * wa.w;
      pb += zv.x * wb.x + zv.y * wb.y + zv.z * wb.z + zv.w * wb.w;
    }
    pa += __shfl_xor(pa, 16); pa += __shfl_xor(pa, 32);
    pb += __shfl_xor(pb, 16); pb += __shfl_xor(pb, 32);
    if (kg4 == 0 && myrow < N) { ta[myrow] = pa; tb[myrow] = pb; }
  } else if (wave == 4) {
    // finalize sv: sum the 4 col-tile partials per row
    int myrow = blk * 64 + lane;
    if (myrow < N) {
      const float* rr = red[lane >> 5][lane & 31];
      sv[myrow] = rr[0] + rr[1] + rr[2] + rr[3];
    }
  }
}

// ---- kernel D: per-edge gather + add
__global__ void kd(const int* __restrict__ ei, const int* __restrict__ mn,
                   const float* __restrict__ ta, const float* __restrict__ tb,
                   const float* __restrict__ sv, const float* __restrict__ b1,
                   float* __restrict__ out, int E) {
  int e = blockIdx.x * blockDim.x + threadIdx.x;
  if (e >= E) return;
  int i0 = ei[e], i1 = ei[E + e];
  int q = (i0 > i1 ? i0 : i1) - mn[0];
  out[e] = ta[i0] + tb[i1] + sv[q] + b1[0];
}

extern "C" void kernel_launch(void* const* d_in, const int* in_sizes, int n_in,
                              void* d_out, int out_size, void* d_ws, size_t ws_size,
                              hipStream_t stream) {
  const float* z  = (const float*)d_in[0];
  const float* z0 = (const float*)d_in[1];
  const int*   ei = (const int*)d_in[2];
  const float* w0 = (const float*)d_in[3];
  const float* pa = (const float*)d_in[4];
  const float* w1 = (const float*)d_in[5];
  const float* b1 = (const float*)d_in[6];
  float* out = (float*)d_out;
  const int N = in_sizes[0] / D_EMB;
  const int E = in_sizes[2] / 2;

  // workspace: [0,4) mn | [256,+192KB) w0 bf16 row-major | ta[N], tb[N], sv[N]
  char* ws = (char*)d_ws;
  int* mn = (int*)ws;
  unsigned short* w0b = (unsigned short*)(ws + 256);
  float* ta = (float*)(ws + 256 + 196608);
  float* tb = ta + N;
  float* sv = tb + N;

  kw<<<(D_EMB * D_NLP / 8 + 255) / 256, 256, 0, stream>>>(w0, w0b, mn);
  km<<<256, 256, 0, stream>>>(ei, E, mn);
  kc<<<(N + 63) / 64, 512, 0, stream>>>(z0, z, w0b, w1, pa, sv, ta, tb, N);
  kd<<<(E + 255) / 256, 256, 0, stream>>>(ei, mn, ta, tb, sv, b1, out, E);
}

// Round 7
// 326.650 us; speedup vs baseline: 1.0164x; 1.0164x over previous
//
#include <hip/hip_runtime.h>
#include <hip/hip_bf16.h>
#include <stdint.h>

#define D_EMB 128
#define D_NLP 768
#define NKC 12       // k-chunks of 64 floats
#define NU 96        // 16B units per w0 row (768 floats / 8)
#define TROWS 128    // rows per tile (8 waves x 16)

typedef __attribute__((ext_vector_type(8))) short bf16x8;
typedef __attribute__((ext_vector_type(4))) float f32x4;
typedef __attribute__((ext_vector_type(8))) unsigned short u16x8;

__device__ __forceinline__ unsigned short f2bf(float f) {
  unsigned u = __builtin_bit_cast(unsigned, f);
  u += 0x7fffu + ((u >> 16) & 1u);   // RTNE (NaN-free inputs)
  return (unsigned short)(u >> 16);
}

__device__ __forceinline__ bf16x8 pack8(const float4& a, const float4& b) {
  u16x8 v;
  v[0] = __builtin_bit_cast(unsigned short, __float2bfloat16(a.x));
  v[1] = __builtin_bit_cast(unsigned short, __float2bfloat16(a.y));
  v[2] = __builtin_bit_cast(unsigned short, __float2bfloat16(a.z));
  v[3] = __builtin_bit_cast(unsigned short, __float2bfloat16(a.w));
  v[4] = __builtin_bit_cast(unsigned short, __float2bfloat16(b.x));
  v[5] = __builtin_bit_cast(unsigned short, __float2bfloat16(b.y));
  v[6] = __builtin_bit_cast(unsigned short, __float2bfloat16(b.z));
  v[7] = __builtin_bit_cast(unsigned short, __float2bfloat16(b.w));
  return __builtin_bit_cast(bf16x8, v);
}

// ---- kernel W: w0 -> bf16, per-row XOR-swizzled 16B units:
// w0s[d*96 + (u ^ (d&7))] = w0[d][u*8 .. u*8+8). Also init mn.
__global__ void kw(const float* __restrict__ w0, unsigned short* __restrict__ w0s,
                   int* __restrict__ mn) {
  int t = blockIdx.x * 256 + threadIdx.x;   // 12288 units
  if (t == 0) mn[0] = 0x7fffffff;
  if (t >= D_EMB * NU) return;
  int d = t / NU, u = t - d * NU;
  const float4* src = (const float4*)(w0 + (size_t)d * D_NLP + u * 8);
  float4 v0 = src[0], v1 = src[1];
  u16x8 o;
  o[0] = f2bf(v0.x); o[1] = f2bf(v0.y); o[2] = f2bf(v0.z); o[3] = f2bf(v0.w);
  o[4] = f2bf(v1.x); o[5] = f2bf(v1.y); o[6] = f2bf(v1.z); o[7] = f2bf(v1.w);
  *(u16x8*)(w0s + ((size_t)d * NU + (u ^ (d & 7))) * 8) = o;
}

// ---- kernel M: mn = min_e max(ei[0][e], ei[1][e])
__global__ void km(const int* __restrict__ ei, int E, int* __restrict__ mn) {
  int t = blockIdx.x * blockDim.x + threadIdx.x;
  int stride = gridDim.x * blockDim.x;
  int m = 0x7fffffff;
  for (int e = t; e < E; e += stride) {
    int a = ei[e], b = ei[E + e];
    int q = a > b ? a : b;
    m = q < m ? q : m;
  }
  #pragma unroll
  for (int off = 32; off; off >>= 1) {
    int o = __shfl_xor(m, off);
    m = o < m ? o : m;
  }
  if ((threadIdx.x & 63) == 0) atomicMin(mn, m);
}

#define LOADA(F, B, T) do {                                         \
    const float4* _p0 = (const float4*)((B) + (T) * 64);            \
    const float4* _p1 = (const float4*)((B) + (T) * 64 + 32);       \
    F[0] = _p0[0]; F[1] = _p0[1]; F[2] = _p1[0]; F[3] = _p1[1];     \
  } while (0)

// cvt current chunk FIRST (frees regs), reissue the slot for chunk T+3, then MFMA.
#define CHUNK(T, F) do {                                                        \
    bf16x8 _a0 = pack8(F[0], F[1]);                                             \
    bf16x8 _a1 = pack8(F[2], F[3]);                                             \
    if ((T) + 3 < NKC) { LOADA(F, aB, (T) + 3); }                               \
    else               { LOADA(F, aN, (T) + 3 - NKC); }                         \
    _Pragma("unroll")                                                           \
    for (int cf = 0; cf < 4; ++cf) {                                            \
      bf16x8 _b0 = *(const bf16x8*)&Bl[(dsb[cf] + (((T)*8 + kg)     ^ dx[cf])) * 8]; \
      acc[cf] = __builtin_amdgcn_mfma_f32_16x16x32_bf16(_a0, _b0, acc[cf], 0, 0, 0); \
      bf16x8 _b1 = *(const bf16x8*)&Bl[(dsb[cf] + (((T)*8 + 4 + kg) ^ dx[cf])) * 8]; \
      acc[cf] = __builtin_amdgcn_mfma_f32_16x16x32_bf16(_a1, _b1, acc[cf], 0, 0, 0); \
    }                                                                           \
  } while (0)

// ---- kernel C: persistent-B, barrier-free main loop.
// 256 blocks (1/CU). Block = (half, p): half = column-half of w0 (64 cols in
// 96KB LDS, filled ONCE); p picks row-tiles p, p+128, ... (128 rows each).
// Launch-index decode co-locates the two halves of a tile-stream on one XCD
// so the duplicate z0 read hits that XCD's L2.
// Main loop: A global->named-reg ring 3 chunks deep, cvt->bf16, 8 ds_read +
// 8 MFMA per chunk; no barriers, no LDS writes -> compiler-counted vmcnt only.
__global__ __launch_bounds__(512, 2) void kc(
    const float* __restrict__ z0, const float* __restrict__ z,
    const unsigned short* __restrict__ w0s, const float* __restrict__ w1,
    const float* __restrict__ prelu_a, float* __restrict__ sv,
    float* __restrict__ pta, float* __restrict__ ptb, int N) {
  extern __shared__ unsigned short Bl[];   // 64 rows x 96 units x 16B = 98304 B

  const int tid = threadIdx.x;
  const int lane = tid & 63;
  const int wave = tid >> 6;        // 0..7
  const int col16 = lane & 15;
  const int kg = lane >> 4;         // 0..3
  const int xcd = blockIdx.x & 7;
  const int slot = blockIdx.x >> 3;
  const int half = slot & 1;
  const int p = xcd * 16 + (slot >> 1);   // 0..127
  const int NT = (N + TROWS - 1) / TROWS;

  // ---- one-time B fill: linear copy of pre-swizzled half into LDS ----
  const unsigned short* w0h = w0s + (size_t)half * 64 * NU * 8;
  #pragma unroll
  for (int it = 0; it < 12; ++it) {
    __builtin_amdgcn_global_load_lds(
        (const __attribute__((address_space(1))) void*)(w0h + ((size_t)it * 512 + tid) * 8),
        (__attribute__((address_space(3))) void*)&Bl[(it * 512 + wave * 64) * 8],
        16, 0, 0);
  }

  int dsb[4], dx[4];
  #pragma unroll
  for (int cf = 0; cf < 4; ++cf) {
    int d = cf * 16 + col16;
    dsb[cf] = d * NU;
    dx[cf] = d & 7;
  }

  f32x4 acc[4];
  #pragma unroll
  for (int cf = 0; cf < 4; ++cf) acc[cf] = (f32x4){0.f, 0.f, 0.f, 0.f};

  float4 fa0[4], fa1[4], fa2[4];

  auto rowptr = [&](int tbase) -> const float* {
    int r = tbase + wave * 16 + col16;
    if (r > N - 1) r = N - 1;
    return z0 + (size_t)r * D_NLP + kg * 8;
  };

  const float* aB = rowptr(p * TROWS);
  LOADA(fa0, aB, 0);
  LOADA(fa1, aB, 1);
  LOADA(fa2, aB, 2);
  __syncthreads();                  // B_lds ready (one-time drain)

  const float apv = prelu_a[0];
  float wcf[4];
  #pragma unroll
  for (int cf = 0; cf < 4; ++cf) wcf[cf] = w1[2 * D_EMB + half * 64 + cf * 16 + col16];
  float* svh = sv + (size_t)half * N;

  for (int t0 = p; t0 < NT; t0 += 128) {
    const int tbase = t0 * TROWS;
    const int tnext = (t0 + 128 < NT) ? t0 + 128 : t0;
    const float* aN = rowptr(tnext * TROWS);

    CHUNK(0, fa0);  CHUNK(1, fa1);  CHUNK(2, fa2);
    CHUNK(3, fa0);  CHUNK(4, fa1);  CHUNK(5, fa2);
    CHUNK(6, fa0);  CHUNK(7, fa1);  CHUNK(8, fa2);
    CHUNK(9, fa0);  CHUNK(10, fa1); CHUNK(11, fa2);
    aB = aN;

    // ---- epilogue: sv for this tile's 128 rows (wave-local, no barrier) ----
    float sp[4];
    #pragma unroll
    for (int i = 0; i < 4; ++i) {
      float s = 0.f;
      #pragma unroll
      for (int cf = 0; cf < 4; ++cf) {
        float h = acc[cf][i];
        float xv = h >= 0.f ? h : apv * h;
        s += xv * wcf[cf];
      }
      sp[i] = s;
    }
    #pragma unroll
    for (int off = 1; off < 16; off <<= 1) {
      #pragma unroll
      for (int i = 0; i < 4; ++i) sp[i] += __shfl_xor(sp[i], off);
    }
    if (col16 == 0) {
      int rb = tbase + wave * 16 + kg * 4;    // C/D row = (lane>>4)*4 + i
      #pragma unroll
      for (int i = 0; i < 4; ++i)
        if (rb + i < N) svh[rb + i] = sp[i];
    }
    #pragma unroll
    for (int cf = 0; cf < 4; ++cf) acc[cf] = (f32x4){0.f, 0.f, 0.f, 0.f};

    // ---- fused kt (half 0 only): ta/tb for this tile's rows ----
    if (half == 0) {
      int myrow = tbase + wave * 16 + col16;
      int rg = myrow > N - 1 ? N - 1 : myrow;
      const float4* zp = (const float4*)(z + (size_t)rg * D_EMB + kg * 32);
      const float4* wa4 = (const float4*)(w1 + kg * 32);
      const float4* wb4 = (const float4*)(w1 + D_EMB + kg * 32);
      float pa = 0.f, pb = 0.f;
      #pragma unroll
      for (int i = 0; i < 8; ++i) {
        float4 zv = zp[i];
        float4 wa = wa4[i];
        float4 wb = wb4[i];
        pa += zv.x * wa.x + zv.y * wa.y + zv.z * wa.z + zv.w * wa.w;
        pb += zv.x * wb.x + zv.y * wb.y + zv.z * wb.z + zv.w * wb.w;
      }
      pa += __shfl_xor(pa, 16); pa += __shfl_xor(pa, 32);
      pb += __shfl_xor(pb, 16); pb += __shfl_xor(pb, 32);
      if (kg == 0 && myrow < N) { pta[myrow] = pa; ptb[myrow] = pb; }
    }
  }
}

// ---- kernel D: per-edge gather + add (sv = two half-partials)
__global__ void kd(const int* __restrict__ ei, const int* __restrict__ mn,
                   const float* __restrict__ ta, const float* __restrict__ tb,
                   const float* __restrict__ sv, const float* __restrict__ b1,
                   float* __restrict__ out, int E, int N) {
  int e = blockIdx.x * blockDim.x + threadIdx.x;
  if (e >= E) return;
  int i0 = ei[e], i1 = ei[E + e];
  int q = (i0 > i1 ? i0 : i1) - mn[0];
  out[e] = ta[i0] + tb[i1] + sv[q] + sv[N + q] + b1[0];
}

extern "C" void kernel_launch(void* const* d_in, const int* in_sizes, int n_in,
                              void* d_out, int out_size, void* d_ws, size_t ws_size,
                              hipStream_t stream) {
  const float* z  = (const float*)d_in[0];
  const float* z0 = (const float*)d_in[1];
  const int*   ei = (const int*)d_in[2];
  const float* w0 = (const float*)d_in[3];
  const float* pa = (const float*)d_in[4];
  const float* w1 = (const float*)d_in[5];
  const float* b1 = (const float*)d_in[6];
  float* out = (float*)d_out;
  const int N = in_sizes[0] / D_EMB;
  const int E = in_sizes[2] / 2;

  // ws: [0,4) mn | [256,+192KB) w0s bf16 swizzled | ta[N] | tb[N] | sv[2N]
  char* ws = (char*)d_ws;
  int* mn = (int*)ws;
  unsigned short* w0s = (unsigned short*)(ws + 256);
  float* ta = (float*)(ws + 256 + 196608);
  float* tb = ta + N;
  float* sv = tb + N;

  hipFuncSetAttribute((const void*)kc,
                      hipFuncAttributeMaxDynamicSharedMemorySize, 98304);

  kw<<<(D_EMB * NU + 255) / 256, 256, 0, stream>>>(w0, w0s, mn);
  km<<<256, 256, 0, stream>>>(ei, E, mn);
  kc<<<256, 512, 98304, stream>>>(z0, z, w0s, w1, pa, sv, ta, tb, N);
  kd<<<(E + 255) / 256, 256, 0, stream>>>(ei, mn, ta, tb, sv, b1, out, E, N);
}

// Round 8
// 130.518 us; speedup vs baseline: 2.5438x; 2.5027x over previous
//
#include <hip/hip_runtime.h>
#include <hip/hip_bf16.h>
#include <stdint.h>

#define D_EMB 128
#define D_NLP 768
#define BM 64
#define BK 64
#define NKC (D_NLP / BK)   // 12 k-chunks

typedef __attribute__((ext_vector_type(8))) short bf16x8;
typedef __attribute__((ext_vector_type(4))) float f32x4;
typedef __attribute__((ext_vector_type(8))) unsigned short u16x8;

__device__ __forceinline__ unsigned short f2bf(float f) {
  unsigned u = __builtin_bit_cast(unsigned, f);
  u += 0x7fffu + ((u >> 16) & 1u);   // RTNE (NaN-free inputs)
  return (unsigned short)(u >> 16);
}

__device__ __forceinline__ bf16x8 pack8(const float4& a, const float4& b) {
  u16x8 v;
  v[0] = __builtin_bit_cast(unsigned short, __float2bfloat16(a.x));
  v[1] = __builtin_bit_cast(unsigned short, __float2bfloat16(a.y));
  v[2] = __builtin_bit_cast(unsigned short, __float2bfloat16(a.z));
  v[3] = __builtin_bit_cast(unsigned short, __float2bfloat16(a.w));
  v[4] = __builtin_bit_cast(unsigned short, __float2bfloat16(b.x));
  v[5] = __builtin_bit_cast(unsigned short, __float2bfloat16(b.y));
  v[6] = __builtin_bit_cast(unsigned short, __float2bfloat16(b.z));
  v[7] = __builtin_bit_cast(unsigned short, __float2bfloat16(b.w));
  return __builtin_bit_cast(bf16x8, v);
}

// ---- kernel W: w0 (128x768 f32) -> bf16, pre-swizzled per k-chunk so a linear
// lane-order copy (global_load_lds) yields the XOR-swizzled LDS layout.
// Also initializes mn.
__global__ void kw(const float* __restrict__ w0, unsigned short* __restrict__ w0s,
                   int* __restrict__ mn) {
  if (blockIdx.x == 0 && threadIdx.x == 0) mn[0] = 0x7fffffff;
  int t = blockIdx.x * 256 + threadIdx.x;       // 12288 threads total
  if (t >= (D_EMB * D_NLP) / 8) return;
  int u = t & 7, row = (t >> 3) & 127, kc = t >> 10;
  const float4* src = (const float4*)(w0 + (size_t)row * D_NLP + kc * BK + ((u ^ (row & 7)) * 8));
  float4 v0 = src[0], v1 = src[1];
  u16x8 o;
  o[0] = f2bf(v0.x); o[1] = f2bf(v0.y); o[2] = f2bf(v0.z); o[3] = f2bf(v0.w);
  o[4] = f2bf(v1.x); o[5] = f2bf(v1.y); o[6] = f2bf(v1.z); o[7] = f2bf(v1.w);
  *(u16x8*)(w0s + (size_t)t * 8) = o;
}

// ---- kernel M: mn = min_e max(ei[0][e], ei[1][e])
__global__ void km(const int* __restrict__ ei, int E, int* __restrict__ mn) {
  int t = blockIdx.x * blockDim.x + threadIdx.x;
  int stride = gridDim.x * blockDim.x;
  int m = 0x7fffffff;
  for (int e = t; e < E; e += stride) {
    int a = ei[e], b = ei[E + e];
    int q = a > b ? a : b;
    m = q < m ? q : m;
  }
  #pragma unroll
  for (int off = 32; off; off >>= 1) {
    int o = __shfl_xor(m, off);
    m = o < m ? o : m;
  }
  if ((threadIdx.x & 63) == 0) atomicMin(mn, m);
}

// ---- kernel C (fused, ring-4 counted-vmcnt pipeline): per 64-node tile:
//   sv[n] = sum_d prelu(z0[n].w0[d,:]) * w1c[d]
//   ta[n] = z[n].w1a, tb[n] = z[n].w1b
// A: global->reg ring of 4 (3 chunks in flight). B: pre-swizzled bf16 w0s via
// global_load_lds into a 4-buffer LDS ring (64KB -> 2 blocks/CU).
// Iter t: s_waitcnt vmcnt(16) (chunks t+1,t+2 stay in flight) -> s_barrier ->
// issue chunk t+3 -> compute chunk t. Cover = 3 compute phases ~ HBM latency.
__global__ __launch_bounds__(256) void kc(
    const float* __restrict__ z0, const float* __restrict__ z,
    const unsigned short* __restrict__ w0s, const float* __restrict__ w1,
    const float* __restrict__ prelu_a, float* __restrict__ sv,
    float* __restrict__ ta, float* __restrict__ tb, int N) {
  __shared__ unsigned short Bb[4][D_EMB * BK];   // 16KB x4 = 64KB

  const int tid = threadIdx.x;
  const int lane = tid & 63;
  const int wave = tid >> 6;
  const int kg = lane >> 4;        // k-group: 8 elems each
  const int col = lane & 15;
  const int myrow = blockIdx.x * BM + wave * 16 + col;
  const int arow_g = min(myrow, N - 1);
  const float* aBase = z0 + (size_t)arow_g * D_NLP + kg * 8;

  f32x4 acc[8];
  #pragma unroll
  for (int c = 0; c < 8; ++c) acc[c] = (f32x4){0.f, 0.f, 0.f, 0.f};

  float4 fa[4][4];   // 3-deep A prefetch ring, statically indexed (unrolled loop)

  auto loadA = [&](int slot, int t) {
    const float4* p0 = (const float4*)(aBase + t * BK);        // ks=0: k = kg*8+[0,8)
    const float4* p1 = (const float4*)(aBase + t * BK + 32);   // ks=1
    fa[slot][0] = p0[0]; fa[slot][1] = p0[1];
    fa[slot][2] = p1[0]; fa[slot][3] = p1[1];
  };

  auto stageB = [&](int t, int buf) {
    const unsigned short* g = w0s + (size_t)t * (D_EMB * BK) + (size_t)tid * 8;
    #pragma unroll
    for (int p = 0; p < 4; ++p) {
      __builtin_amdgcn_global_load_lds(
          (const __attribute__((address_space(1))) void*)(g + p * 256 * 8),
          (__attribute__((address_space(3))) void*)&Bb[buf][(wave * 64 + p * 256) * 8],
          16, 0, 0);
    }
  };

  // prologue: chunks 0,1,2 in flight (24 vmem ops)
  loadA(0, 0); stageB(0, 0);
  loadA(1, 1); stageB(1, 1);
  loadA(2, 2); stageB(2, 2);

  #pragma unroll
  for (int t = 0; t < NKC; ++t) {
    // wait for chunk t only; chunks t+1, t+2 (16 ops) stay in flight.
    // vmcnt retires in order, so <=16 outstanding proves chunk t landed.
    if (t <= NKC - 3)      asm volatile("s_waitcnt vmcnt(16)" ::: "memory");
    else if (t == NKC - 2) asm volatile("s_waitcnt vmcnt(8)" ::: "memory");
    else                   asm volatile("s_waitcnt vmcnt(0)" ::: "memory");
    __builtin_amdgcn_s_barrier();         // all waves' chunk-t stage landed
    if (t + 3 < NKC) {                    // issue chunk t+3 into ring slot
      loadA((t + 3) & 3, t + 3);
      stageB(t + 3, (t + 3) & 3);
    }
    __builtin_amdgcn_sched_barrier(0);    // pin issue block above compute

    const float4* f = fa[t & 3];
    bf16x8 af0 = pack8(f[0], f[1]);
    bf16x8 af1 = pack8(f[2], f[3]);

    const unsigned short* Bbuf = Bb[t & 3];
    #pragma unroll
    for (int ks = 0; ks < 2; ++ks) {
      bf16x8 af = ks == 0 ? af0 : af1;
      #pragma unroll
      for (int c = 0; c < 8; ++c) {
        int brow = c * 16 + col;
        bf16x8 bfr = *(const bf16x8*)&Bbuf[(brow * 8 + ((ks * 4 + kg) ^ (brow & 7))) * 8];
        acc[c] = __builtin_amdgcn_mfma_f32_16x16x32_bf16(af, bfr, acc[c], 0, 0, 0);
      }
    }
  }

  // epilogue 1: prelu + * w1c[col-block], reduce the 16 cols held per lane-group
  float ap = prelu_a[0];
  float ssum[4] = {0.f, 0.f, 0.f, 0.f};
  #pragma unroll
  for (int c = 0; c < 8; ++c) {
    float wc = w1[2 * D_EMB + c * 16 + col];
    #pragma unroll
    for (int i = 0; i < 4; ++i) {
      float h = acc[c][i];
      float x = h >= 0.f ? h : ap * h;
      ssum[i] += x * wc;
    }
  }
  #pragma unroll
  for (int off = 1; off < 16; off <<= 1) {
    #pragma unroll
    for (int i = 0; i < 4; ++i) ssum[i] += __shfl_xor(ssum[i], off);
  }
  if (col == 0) {
    int rbase = blockIdx.x * BM + wave * 16 + kg * 4;   // D row = (lane>>4)*4 + i
    #pragma unroll
    for (int i = 0; i < 4; ++i) {
      int r = rbase + i;
      if (r < N) sv[r] = ssum[i];
    }
  }

  // epilogue 2 (fused kt): ta/tb for this block's 64 rows; row = col, kg splits D_EMB.
  {
    const float* zp = z + (size_t)arow_g * D_EMB + kg * 32;
    const float4* wa4 = (const float4*)(w1 + kg * 32);
    const float4* wb4 = (const float4*)(w1 + D_EMB + kg * 32);
    float pa = 0.f, pb = 0.f;
    #pragma unroll
    for (int i = 0; i < 8; ++i) {
      float4 zv = ((const float4*)zp)[i];
      float4 wa = wa4[i];
      float4 wb = wb4[i];
      pa += zv.x * wa.x + zv.y * wa.y + zv.z * wa.z + zv.w * wa.w;
      pb += zv.x * wb.x + zv.y * wb.y + zv.z * wb.z + zv.w * wb.w;
    }
    pa += __shfl_xor(pa, 16); pa += __shfl_xor(pa, 32);
    pb += __shfl_xor(pb, 16); pb += __shfl_xor(pb, 32);
    if (kg == 0 && myrow < N) { ta[myrow] = pa; tb[myrow] = pb; }
  }
}

// ---- kernel D: per-edge gather + add
__global__ void kd(const int* __restrict__ ei, const int* __restrict__ mn,
                   const float* __restrict__ ta, const float* __restrict__ tb,
                   const float* __restrict__ sv, const float* __restrict__ b1,
                   float* __restrict__ out, int E) {
  int e = blockIdx.x * blockDim.x + threadIdx.x;
  if (e >= E) return;
  int i0 = ei[e], i1 = ei[E + e];
  int q = (i0 > i1 ? i0 : i1) - mn[0];
  out[e] = ta[i0] + tb[i1] + sv[q] + b1[0];
}

extern "C" void kernel_launch(void* const* d_in, const int* in_sizes, int n_in,
                              void* d_out, int out_size, void* d_ws, size_t ws_size,
                              hipStream_t stream) {
  const float* z  = (const float*)d_in[0];
  const float* z0 = (const float*)d_in[1];
  const int*   ei = (const int*)d_in[2];
  const float* w0 = (const float*)d_in[3];
  const float* pa = (const float*)d_in[4];
  const float* w1 = (const float*)d_in[5];
  const float* b1 = (const float*)d_in[6];
  float* out = (float*)d_out;
  const int N = in_sizes[0] / D_EMB;
  const int E = in_sizes[2] / 2;

  // workspace layout (~1.4 MB):
  // [0,4) mn | [256, 256+196608) w0 bf16 pre-swizzled | ta[N], tb[N], sv[N] f32
  char* ws = (char*)d_ws;
  int* mn = (int*)ws;
  unsigned short* w0s = (unsigned short*)(ws + 256);
  float* ta = (float*)(ws + 256 + 196608);
  float* tb = ta + N;
  float* sv = tb + N;

  kw<<<(D_EMB * D_NLP / 8 + 255) / 256, 256, 0, stream>>>(w0, w0s, mn);
  km<<<256, 256, 0, stream>>>(ei, E, mn);
  kc<<<(N + BM - 1) / BM, 256, 0, stream>>>(z0, z, w0s, w1, pa, sv, ta, tb, N);
  kd<<<(E + 255) / 256, 256, 0, stream>>>(ei, mn, ta, tb, sv, b1, out, E);
}

// Round 9
// 126.444 us; speedup vs baseline: 2.6257x; 1.0322x over previous
//
#include <hip/hip_runtime.h>
#include <hip/hip_bf16.h>
#include <stdint.h>

#define D_EMB 128
#define D_NLP 768
#define BM 64
#define NSC 6          // super-chunks of 128 floats (2x 64-k chunks)

typedef __attribute__((ext_vector_type(8))) short bf16x8;
typedef __attribute__((ext_vector_type(4))) float f32x4;
typedef __attribute__((ext_vector_type(8))) unsigned short u16x8;

__device__ __forceinline__ unsigned short f2bf(float f) {
  unsigned u = __builtin_bit_cast(unsigned, f);
  u += 0x7fffu + ((u >> 16) & 1u);   // RTNE (NaN-free inputs)
  return (unsigned short)(u >> 16);
}

__device__ __forceinline__ bf16x8 pack8(const float4& a, const float4& b) {
  u16x8 v;
  v[0] = __builtin_bit_cast(unsigned short, __float2bfloat16(a.x));
  v[1] = __builtin_bit_cast(unsigned short, __float2bfloat16(a.y));
  v[2] = __builtin_bit_cast(unsigned short, __float2bfloat16(a.z));
  v[3] = __builtin_bit_cast(unsigned short, __float2bfloat16(a.w));
  v[4] = __builtin_bit_cast(unsigned short, __float2bfloat16(b.x));
  v[5] = __builtin_bit_cast(unsigned short, __float2bfloat16(b.y));
  v[6] = __builtin_bit_cast(unsigned short, __float2bfloat16(b.z));
  v[7] = __builtin_bit_cast(unsigned short, __float2bfloat16(b.w));
  return __builtin_bit_cast(bf16x8, v);
}

// ---- kernel W: w0 (128x768 f32) -> bf16, pre-swizzled per 64-k chunk so a
// linear lane-order copy (global_load_lds) yields the XOR-swizzled LDS layout.
__global__ void kw(const float* __restrict__ w0, unsigned short* __restrict__ w0s,
                   int* __restrict__ mn) {
  if (blockIdx.x == 0 && threadIdx.x == 0) mn[0] = 0x7fffffff;
  int t = blockIdx.x * 256 + threadIdx.x;       // 12288 units
  if (t >= (D_EMB * D_NLP) / 8) return;
  int u = t & 7, row = (t >> 3) & 127, kc = t >> 10;
  const float4* src = (const float4*)(w0 + (size_t)row * D_NLP + kc * 64 + ((u ^ (row & 7)) * 8));
  float4 v0 = src[0], v1 = src[1];
  u16x8 o;
  o[0] = f2bf(v0.x); o[1] = f2bf(v0.y); o[2] = f2bf(v0.z); o[3] = f2bf(v0.w);
  o[4] = f2bf(v1.x); o[5] = f2bf(v1.y); o[6] = f2bf(v1.z); o[7] = f2bf(v1.w);
  *(u16x8*)(w0s + (size_t)t * 8) = o;
}

// ---- kernel M: mn = min_e max(ei[0][e], ei[1][e])
__global__ void km(const int* __restrict__ ei, int E, int* __restrict__ mn) {
  int t = blockIdx.x * blockDim.x + threadIdx.x;
  int stride = gridDim.x * blockDim.x;
  int m = 0x7fffffff;
  for (int e = t; e < E; e += stride) {
    int a = ei[e], b = ei[E + e];
    int q = a > b ? a : b;
    m = q < m ? q : m;
  }
  #pragma unroll
  for (int off = 32; off; off >>= 1) {
    int o = __shfl_xor(m, off);
    m = o < m ? o : m;
  }
  if ((threadIdx.x & 63) == 0) atomicMin(mn, m);
}

// A burst: 8 float4 = this lane's share of a 128-float super-chunk; per row the
// wave covers 512 CONTIGUOUS bytes (DRAM page-friendly).
#define LOADA2(F, SC) do {                                                   \
    _Pragma("unroll")                                                        \
    for (int _s = 0; _s < 4; ++_s) {                                         \
      const float4* _p = (const float4*)(aBase + (SC) * 128 + _s * 32);      \
      F[2 * _s] = _p[0];                                                     \
      F[2 * _s + 1] = _p[1];                                                 \
    }                                                                        \
  } while (0)

#define STAGEB(SC, BUF) do {                                                 \
    const unsigned short* _g = w0s + (size_t)(SC) * 16384 + (size_t)tid * 8; \
    _Pragma("unroll")                                                        \
    for (int _p = 0; _p < 8; ++_p) {                                         \
      __builtin_amdgcn_global_load_lds(                                      \
          (const __attribute__((address_space(1))) void*)(_g + _p * 2048),   \
          (__attribute__((address_space(3))) void*)&Bb[BUF][(_p * 256 + wave * 64) * 8], \
          16, 0, 0);                                                         \
    }                                                                        \
  } while (0)

// One super-chunk: wait (counted) -> barrier -> compute -> barrier -> issue T+2.
#define SUPER(T, F, VM) do {                                                 \
    asm volatile("s_waitcnt vmcnt(" #VM ")" ::: "memory");                   \
    __builtin_amdgcn_s_barrier();                                            \
    __builtin_amdgcn_sched_barrier(0);                                       \
    bf16x8 _af0 = pack8(F[0], F[1]);                                         \
    bf16x8 _af1 = pack8(F[2], F[3]);                                         \
    bf16x8 _af2 = pack8(F[4], F[5]);                                         \
    bf16x8 _af3 = pack8(F[6], F[7]);                                         \
    _Pragma("unroll")                                                        \
    for (int _s = 0; _s < 4; ++_s) {                                         \
      bf16x8 _af = _s == 0 ? _af0 : _s == 1 ? _af1 : _s == 2 ? _af2 : _af3;  \
      const int _h = _s >> 1, _sl = _s & 1;                                  \
      _Pragma("unroll")                                                      \
      for (int _c = 0; _c < 8; ++_c) {                                       \
        int _brow = _c * 16 + col;                                           \
        bf16x8 _bf = *(const bf16x8*)&Bb[(T) & 1][_h * 8192 +                \
            (_brow * 8 + (((_sl * 4 + kg)) ^ (_brow & 7))) * 8];             \
        acc[_c] = __builtin_amdgcn_mfma_f32_16x16x32_bf16(_af, _bf, acc[_c], 0, 0, 0); \
      }                                                                      \
    }                                                                        \
    if ((T) + 2 < NSC) {                                                     \
      __builtin_amdgcn_sched_barrier(0);                                     \
      __builtin_amdgcn_s_barrier();  /* all waves done reading buf (T)&1 */  \
      __builtin_amdgcn_sched_barrier(0);                                     \
      LOADA2(F, (T) + 2);                                                    \
      STAGEB((T) + 2, (T) & 1);                                              \
      __builtin_amdgcn_sched_barrier(0);                                     \
    }                                                                        \
  } while (0)

// ---- kernel C (fused): per 64-node tile:
//   sv[n] = sum_d prelu(z0[n].w0[d,:]) * w1c[d]
//   ta[n] = z[n].w1a, tb[n] = z[n].w1b
// BK=128 super-chunks: per-row 512B contiguous A bursts (DRAM page locality),
// 2x32KB LDS B ring (2 blocks/CU), counted vmcnt(16), raw barriers (no drain).
__global__ __launch_bounds__(256) void kc(
    const float* __restrict__ z0, const float* __restrict__ z,
    const unsigned short* __restrict__ w0s, const float* __restrict__ w1,
    const float* __restrict__ prelu_a, float* __restrict__ sv,
    float* __restrict__ ta, float* __restrict__ tb, int N) {
  __shared__ unsigned short Bb[2][16384];   // 32KB x2

  const int tid = threadIdx.x;
  const int lane = tid & 63;
  const int wave = tid >> 6;
  const int kg = lane >> 4;        // k-group: 8 floats each
  const int col = lane & 15;
  const int myrow = blockIdx.x * BM + wave * 16 + col;
  const int arow_g = min(myrow, N - 1);
  const float* aBase = z0 + (size_t)arow_g * D_NLP + kg * 8;

  f32x4 acc[8];
  #pragma unroll
  for (int c = 0; c < 8; ++c) acc[c] = (f32x4){0.f, 0.f, 0.f, 0.f};

  float4 fa0[8], fa1[8];   // A ring, statically indexed via macro args

  // prologue: supers 0 and 1 in flight (16 ops each)
  LOADA2(fa0, 0); STAGEB(0, 0);
  LOADA2(fa1, 1); STAGEB(1, 1);

  SUPER(0, fa0, 16);
  SUPER(1, fa1, 16);
  SUPER(2, fa0, 16);
  SUPER(3, fa1, 16);
  SUPER(4, fa0, 16);
  SUPER(5, fa1, 0);

  // epilogue 1: prelu + * w1c[col-block], reduce the 16 cols held per lane-group
  float ap = prelu_a[0];
  float ssum[4] = {0.f, 0.f, 0.f, 0.f};
  #pragma unroll
  for (int c = 0; c < 8; ++c) {
    float wc = w1[2 * D_EMB + c * 16 + col];
    #pragma unroll
    for (int i = 0; i < 4; ++i) {
      float h = acc[c][i];
      float x = h >= 0.f ? h : ap * h;
      ssum[i] += x * wc;
    }
  }
  #pragma unroll
  for (int off = 1; off < 16; off <<= 1) {
    #pragma unroll
    for (int i = 0; i < 4; ++i) ssum[i] += __shfl_xor(ssum[i], off);
  }
  if (col == 0) {
    int rbase = blockIdx.x * BM + wave * 16 + kg * 4;   // D row = (lane>>4)*4 + i
    #pragma unroll
    for (int i = 0; i < 4; ++i) {
      int r = rbase + i;
      if (r < N) sv[r] = ssum[i];
    }
  }

  // epilogue 2 (fused kt): ta/tb for this block's 64 rows; row = col, kg splits D_EMB.
  {
    const float* zp = z + (size_t)arow_g * D_EMB + kg * 32;
    const float4* wa4 = (const float4*)(w1 + kg * 32);
    const float4* wb4 = (const float4*)(w1 + D_EMB + kg * 32);
    float pa = 0.f, pb = 0.f;
    #pragma unroll
    for (int i = 0; i < 8; ++i) {
      float4 zv = ((const float4*)zp)[i];
      float4 wa = wa4[i];
      float4 wb = wb4[i];
      pa += zv.x * wa.x + zv.y * wa.y + zv.z * wa.z + zv.w * wa.w;
      pb += zv.x * wb.x + zv.y * wb.y + zv.z * wb.z + zv.w * wb.w;
    }
    pa += __shfl_xor(pa, 16); pa += __shfl_xor(pa, 32);
    pb += __shfl_xor(pb, 16); pb += __shfl_xor(pb, 32);
    if (kg == 0 && myrow < N) { ta[myrow] = pa; tb[myrow] = pb; }
  }
}

// ---- kernel D: per-edge gather + add
__global__ void kd(const int* __restrict__ ei, const int* __restrict__ mn,
                   const float* __restrict__ ta, const float* __restrict__ tb,
                   const float* __restrict__ sv, const float* __restrict__ b1,
                   float* __restrict__ out, int E) {
  int e = blockIdx.x * blockDim.x + threadIdx.x;
  if (e >= E) return;
  int i0 = ei[e], i1 = ei[E + e];
  int q = (i0 > i1 ? i0 : i1) - mn[0];
  out[e] = ta[i0] + tb[i1] + sv[q] + b1[0];
}

extern "C" void kernel_launch(void* const* d_in, const int* in_sizes, int n_in,
                              void* d_out, int out_size, void* d_ws, size_t ws_size,
                              hipStream_t stream) {
  const float* z  = (const float*)d_in[0];
  const float* z0 = (const float*)d_in[1];
  const int*   ei = (const int*)d_in[2];
  const float* w0 = (const float*)d_in[3];
  const float* pa = (const float*)d_in[4];
  const float* w1 = (const float*)d_in[5];
  const float* b1 = (const float*)d_in[6];
  float* out = (float*)d_out;
  const int N = in_sizes[0] / D_EMB;
  const int E = in_sizes[2] / 2;

  // workspace layout (~1.4 MB):
  // [0,4) mn | [256, 256+196608) w0 bf16 pre-swizzled | ta[N], tb[N], sv[N] f32
  char* ws = (char*)d_ws;
  int* mn = (int*)ws;
  unsigned short* w0s = (unsigned short*)(ws + 256);
  float* ta = (float*)(ws + 256 + 196608);
  float* tb = ta + N;
  float* sv = tb + N;

  kw<<<(D_EMB * D_NLP / 8 + 255) / 256, 256, 0, stream>>>(w0, w0s, mn);
  km<<<256, 256, 0, stream>>>(ei, E, mn);
  kc<<<(N + BM - 1) / BM, 256, 0, stream>>>(z0, z, w0s, w1, pa, sv, ta, tb, N);
  kd<<<(E + 255) / 256, 256, 0, stream>>>(ei, mn, ta, tb, sv, b1, out, E);
}